// Round 2
// baseline (441.862 us; speedup 1.0000x reference)
//
#include <hip/hip_runtime.h>

// LIF neuron forward scan, x: [B=64, F=2048, T=512] f32 (scan over contiguous T).
//   v = v + (x_t - v) * (DT/TAU);  s = (v >= 1); v *= (1 - s)
//
// Structure: one wave (64 threads) per block, 64 rows/block, T chunked by 64.
// 16 KB LDS transpose tile with per-element XOR swizzle tile[c][r^c] --
// conflict-free (2 lanes/bank) in both the coalesced staging phase and the
// lane-per-row sequential scan. NO __syncthreads: single-wave blocks mean all
// LDS hazards are intra-wave and in-order; phases are fenced with raw
// s_waitcnt lgkmcnt(0) + "memory" clobber, so the prefetched global loads for
// chunk ch+1 (register double-buffer) stay in flight across the whole
// compute+store of chunk ch instead of being drained by the barrier's
// vmcnt(0) (hipcc drains all counters at s_barrier).

#define T_LEN 512
#define CHUNK 64
#define NCHUNK (T_LEN / CHUNK)

__global__ __launch_bounds__(64, 2)
void lif_kernel(const float* __restrict__ x, float* __restrict__ out) {
    __shared__ float tile[CHUNK][64];   // 16 KB, XOR-swizzled columns
    const int lane = threadIdx.x;                 // 0..63
    const size_t row0 = (size_t)blockIdx.x * 64;  // 64 rows per block
    const float kk = 1.0f / 20.0f;                // DT / TAU
    float v = 0.0f;                               // membrane potential

    const float* xb = x + row0 * T_LEN;
    float* ob = out + row0 * T_LEN;

    // Per-lane staging geometry: q = p*64+lane; r = q>>4; c = (q&15)*4.
    // Lanes 0..15 cover one row's 64-float chunk contiguously (256 B/segment).
    const int rL = lane >> 4;          // row sub-index 0..3
    const int cL = (lane & 15) * 4;    // t offset within chunk, 0..60

    float4 buf[16];                    // register double-buffer (64 VGPRs)

    // prologue: load chunk 0
    #pragma unroll
    for (int p = 0; p < 16; ++p) {
        const int r = p * 4 + rL;
        buf[p] = *reinterpret_cast<const float4*>(xb + (size_t)r * T_LEN + cL);
    }

    for (int ch = 0; ch < NCHUNK; ++ch) {
        // ---- regs -> LDS (swizzled scalar writes, conflict-free) ----
        #pragma unroll
        for (int p = 0; p < 16; ++p) {
            const int r = p * 4 + rL;
            tile[cL + 0][r ^ (cL + 0)] = buf[p].x;
            tile[cL + 1][r ^ (cL + 1)] = buf[p].y;
            tile[cL + 2][r ^ (cL + 2)] = buf[p].z;
            tile[cL + 3][r ^ (cL + 3)] = buf[p].w;
        }

        // ---- issue next chunk's global loads; they stay in flight across
        //      the compute+store phases (no barrier -> no vmcnt drain) ----
        if (ch + 1 < NCHUNK) {
            const float* xc = xb + (size_t)(ch + 1) * CHUNK;
            #pragma unroll
            for (int p = 0; p < 16; ++p) {
                const int r = p * 4 + rL;
                buf[p] = *reinterpret_cast<const float4*>(xc + (size_t)r * T_LEN + cL);
            }
        }

        asm volatile("s_waitcnt lgkmcnt(0)" ::: "memory");

        // ---- sequential LIF scan; lane owns row row0+lane ----
        #pragma unroll
        for (int t = 0; t < CHUNK; ++t) {
            const float xv = tile[t][lane ^ t];
            v = v + (xv - v) * kk;
            const bool fire = (v >= 1.0f);
            tile[t][lane ^ t] = fire ? 1.0f : 0.0f;   // spike out, in place
            v = fire ? 0.0f : v;                      // hard reset
        }

        asm volatile("s_waitcnt lgkmcnt(0)" ::: "memory");

        // ---- LDS -> global (coalesced float4 stores) ----
        float* oc = ob + (size_t)ch * CHUNK;
        #pragma unroll
        for (int p = 0; p < 16; ++p) {
            const int r = p * 4 + rL;
            float4 s;
            s.x = tile[cL + 0][r ^ (cL + 0)];
            s.y = tile[cL + 1][r ^ (cL + 1)];
            s.z = tile[cL + 2][r ^ (cL + 2)];
            s.w = tile[cL + 3][r ^ (cL + 3)];
            *reinterpret_cast<float4*>(oc + (size_t)r * T_LEN + cL) = s;
        }

        // order store-phase ds_reads before next iteration's staging writes
        asm volatile("s_waitcnt lgkmcnt(0)" ::: "memory");
    }
}

extern "C" void kernel_launch(void* const* d_in, const int* in_sizes, int n_in,
                              void* d_out, int out_size, void* d_ws, size_t ws_size,
                              hipStream_t stream) {
    const float* x = (const float*)d_in[0];
    float* out = (float*)d_out;
    const int rows = in_sizes[0] / T_LEN;   // B*F = 131072
    const int grid = rows / 64;             // 2048 single-wave blocks
    lif_kernel<<<dim3(grid), dim3(64), 0, stream>>>(x, out);
}